// Round 1
// baseline (608.125 us; speedup 1.0000x reference)
//
#include <hip/hip_runtime.h>
#include <math.h>

#define N_NODES 50000
#define N_EDGES 800000
#define HDIM 128
#define NLAYERS 4
#define LN_EPS 1e-5f

// ---------------- CSR build ----------------

__global__ void deg_count_kernel(const int* __restrict__ dst, int* __restrict__ degcnt) {
    int e = blockIdx.x * blockDim.x + threadIdx.x;
    if (e < N_EDGES) atomicAdd(&degcnt[dst[e]], 1);
}

__global__ void scan1_kernel(const int* __restrict__ degcnt, int* __restrict__ partial,
                             int* __restrict__ blocksum) {
    __shared__ int buf[256];
    int tid = threadIdx.x;
    int i = blockIdx.x * 256 + tid;
    int v = (i < N_NODES) ? degcnt[i] : 0;
    buf[tid] = v;
    __syncthreads();
    for (int off = 1; off < 256; off <<= 1) {
        int t = (tid >= off) ? buf[tid - off] : 0;
        __syncthreads();
        buf[tid] += t;
        __syncthreads();
    }
    if (i < N_NODES) partial[i] = buf[tid] - v;  // exclusive
    if (tid == 255) blocksum[blockIdx.x] = buf[255];
}

__global__ void scan2_kernel(int* __restrict__ blocksum, int nblk) {
    __shared__ int buf[256];
    int tid = threadIdx.x;
    int v = (tid < nblk) ? blocksum[tid] : 0;
    buf[tid] = v;
    __syncthreads();
    for (int off = 1; off < 256; off <<= 1) {
        int t = (tid >= off) ? buf[tid - off] : 0;
        __syncthreads();
        buf[tid] += t;
        __syncthreads();
    }
    if (tid < nblk) blocksum[tid] = buf[tid] - v;  // exclusive
}

__global__ void scan3_kernel(const int* __restrict__ degcnt, const int* __restrict__ partial,
                             const int* __restrict__ blocksum, int* __restrict__ offs,
                             int* __restrict__ cursor, float* __restrict__ isd,
                             float* __restrict__ ind) {
    int i = blockIdx.x * blockDim.x + threadIdx.x;
    if (i < N_NODES) {
        int o = partial[i] + blocksum[i >> 8];
        offs[i] = o;
        cursor[i] = o;
        float d = (float)degcnt[i] + 1.0f;  // self-loop
        isd[i] = rsqrtf(d);
        ind[i] = 1.0f / d;
        if (i == 0) offs[N_NODES] = N_EDGES;
    }
}

__global__ void fill_kernel(const int* __restrict__ src, const int* __restrict__ dst,
                            const float* __restrict__ isd, int* __restrict__ cursor,
                            int* __restrict__ csr_src, float* __restrict__ csr_w) {
    int e = blockIdx.x * blockDim.x + threadIdx.x;
    if (e < N_EDGES) {
        int s = src[e], d = dst[e];
        int p = atomicAdd(&cursor[d], 1);
        csr_src[p] = s;
        csr_w[p] = isd[s] * isd[d];
    }
}

// ---------------- GEMM: hw = h @ W  (M=N_NODES, K=128, N=128), fp32 ----------------
// Block: 256 threads, 64 rows x 128 cols per block. Thread: 4 rows x 8 cols.
#define BM 64
#define KC 32

__global__ __launch_bounds__(256) void gemm_kernel(const float* __restrict__ A,
                                                   const float* __restrict__ W,
                                                   float* __restrict__ out) {
    __shared__ float As[BM][36];        // pad: stride 36 floats (144 B, 16B-aligned rows)
    __shared__ float Ws[KC][HDIM];
    int tid = threadIdx.x;
    int tc = tid & 15;   // col group: cols tc*8 .. tc*8+7
    int tr = tid >> 4;   // row group: rows tr*4 .. tr*4+3
    int rowBase = blockIdx.x * BM;

    float acc[4][8];
#pragma unroll
    for (int r = 0; r < 4; ++r)
#pragma unroll
        for (int j = 0; j < 8; ++j) acc[r][j] = 0.f;

    for (int kc = 0; kc < HDIM; kc += KC) {
        // stage A: 64 rows x 32 cols = 512 float4
        for (int f = tid; f < 512; f += 256) {
            int r = f >> 3;
            int c4 = f & 7;
            int grow = rowBase + r;
            float4 v = make_float4(0.f, 0.f, 0.f, 0.f);
            if (grow < N_NODES) v = *(const float4*)&A[(size_t)grow * HDIM + kc + c4 * 4];
            *(float4*)&As[r][c4 * 4] = v;
        }
        // stage W chunk: contiguous 32x128 = 1024 float4
        const float4* Wg = (const float4*)(W + (size_t)kc * HDIM);
        float4* Wl = (float4*)&Ws[0][0];
        for (int f = tid; f < 1024; f += 256) Wl[f] = Wg[f];
        __syncthreads();

#pragma unroll
        for (int k = 0; k < KC; ++k) {
            float a0 = As[tr * 4 + 0][k];
            float a1 = As[tr * 4 + 1][k];
            float a2 = As[tr * 4 + 2][k];
            float a3 = As[tr * 4 + 3][k];
            float4 w0 = *(float4*)&Ws[k][tc * 8];
            float4 w1 = *(float4*)&Ws[k][tc * 8 + 4];
            acc[0][0] = fmaf(a0, w0.x, acc[0][0]); acc[0][1] = fmaf(a0, w0.y, acc[0][1]);
            acc[0][2] = fmaf(a0, w0.z, acc[0][2]); acc[0][3] = fmaf(a0, w0.w, acc[0][3]);
            acc[0][4] = fmaf(a0, w1.x, acc[0][4]); acc[0][5] = fmaf(a0, w1.y, acc[0][5]);
            acc[0][6] = fmaf(a0, w1.z, acc[0][6]); acc[0][7] = fmaf(a0, w1.w, acc[0][7]);
            acc[1][0] = fmaf(a1, w0.x, acc[1][0]); acc[1][1] = fmaf(a1, w0.y, acc[1][1]);
            acc[1][2] = fmaf(a1, w0.z, acc[1][2]); acc[1][3] = fmaf(a1, w0.w, acc[1][3]);
            acc[1][4] = fmaf(a1, w1.x, acc[1][4]); acc[1][5] = fmaf(a1, w1.y, acc[1][5]);
            acc[1][6] = fmaf(a1, w1.z, acc[1][6]); acc[1][7] = fmaf(a1, w1.w, acc[1][7]);
            acc[2][0] = fmaf(a2, w0.x, acc[2][0]); acc[2][1] = fmaf(a2, w0.y, acc[2][1]);
            acc[2][2] = fmaf(a2, w0.z, acc[2][2]); acc[2][3] = fmaf(a2, w0.w, acc[2][3]);
            acc[2][4] = fmaf(a2, w1.x, acc[2][4]); acc[2][5] = fmaf(a2, w1.y, acc[2][5]);
            acc[2][6] = fmaf(a2, w1.z, acc[2][6]); acc[2][7] = fmaf(a2, w1.w, acc[2][7]);
            acc[3][0] = fmaf(a3, w0.x, acc[3][0]); acc[3][1] = fmaf(a3, w0.y, acc[3][1]);
            acc[3][2] = fmaf(a3, w0.z, acc[3][2]); acc[3][3] = fmaf(a3, w0.w, acc[3][3]);
            acc[3][4] = fmaf(a3, w1.x, acc[3][4]); acc[3][5] = fmaf(a3, w1.y, acc[3][5]);
            acc[3][6] = fmaf(a3, w1.z, acc[3][6]); acc[3][7] = fmaf(a3, w1.w, acc[3][7]);
        }
        __syncthreads();
    }

#pragma unroll
    for (int r = 0; r < 4; ++r) {
        int grow = rowBase + tr * 4 + r;
        if (grow < N_NODES) {
            float4 o0 = make_float4(acc[r][0], acc[r][1], acc[r][2], acc[r][3]);
            float4 o1 = make_float4(acc[r][4], acc[r][5], acc[r][6], acc[r][7]);
            *(float4*)&out[(size_t)grow * HDIM + tc * 8] = o0;
            *(float4*)&out[(size_t)grow * HDIM + tc * 8 + 4] = o1;
        }
    }
}

// ---------------- Fused aggregate + self-loop + bias + LN (+GELU / +head) ----------------
// One wave (64 lanes) per node; each lane owns 2 columns (float2).
__global__ __launch_bounds__(256) void agg_ln_kernel(
    const float* __restrict__ hw, const int* __restrict__ offs,
    const int* __restrict__ csr_src, const float* __restrict__ csr_w,
    const float* __restrict__ ind, const float* __restrict__ conv_b,
    const float* __restrict__ ln_g, const float* __restrict__ ln_b,
    float* __restrict__ hout, const float* __restrict__ head_w,
    const float* __restrict__ head_b, float* __restrict__ scores,
    int do_gelu, int do_head) {
    int wave = threadIdx.x >> 6;
    int lane = threadIdx.x & 63;
    int n = blockIdx.x * 4 + wave;
    if (n >= N_NODES) return;
    int c = lane * 2;

    float2 hv = *(const float2*)&hw[(size_t)n * HDIM + c];
    float idn = ind[n];
    float2 cb = *(const float2*)&conv_b[c];
    float ax = fmaf(hv.x, idn, cb.x);
    float ay = fmaf(hv.y, idn, cb.y);

    int rs = offs[n], re = offs[n + 1];
    for (int base = rs; base < re; base += 64) {
        int m = re - base;
        if (m > 64) m = 64;
        int sj = 0;
        float wj = 0.f;
        if (lane < m) { sj = csr_src[base + lane]; wj = csr_w[base + lane]; }
        for (int j = 0; j < m; ++j) {
            int s = __shfl(sj, j);
            float w = __shfl(wj, j);
            float2 v = *(const float2*)&hw[(size_t)s * HDIM + c];
            ax = fmaf(v.x, w, ax);
            ay = fmaf(v.y, w, ay);
        }
    }

    // LayerNorm across the 128 columns of this wave
    float sum = ax + ay;
#pragma unroll
    for (int o = 32; o; o >>= 1) sum += __shfl_xor(sum, o);
    float mu = sum * (1.0f / HDIM);
    float dx = ax - mu, dy = ay - mu;
    float vs = dx * dx + dy * dy;
#pragma unroll
    for (int o = 32; o; o >>= 1) vs += __shfl_xor(vs, o);
    float rstd = rsqrtf(vs * (1.0f / HDIM) + LN_EPS);
    float2 g = *(const float2*)&ln_g[c];
    float2 b = *(const float2*)&ln_b[c];
    float yx = fmaf(dx * rstd, g.x, b.x);
    float yy = fmaf(dy * rstd, g.y, b.y);
    if (do_gelu) {
        yx = 0.5f * yx * (1.0f + erff(yx * 0.70710678118654752f));
        yy = 0.5f * yy * (1.0f + erff(yy * 0.70710678118654752f));
    }
    *(float2*)&hout[(size_t)n * HDIM + c] = make_float2(yx, yy);

    if (do_head) {
        float2 hwv = *(const float2*)&head_w[c];
        float p = yx * hwv.x + yy * hwv.y;
#pragma unroll
        for (int o = 32; o; o >>= 1) p += __shfl_xor(p, o);
        if (lane == 0) scores[n] = p + head_b[0];
    }
}

// ---------------- host ----------------

extern "C" void kernel_launch(void* const* d_in, const int* in_sizes, int n_in,
                              void* d_out, int out_size, void* d_ws, size_t ws_size,
                              hipStream_t stream) {
    const float* x      = (const float*)d_in[0];
    const int*   eidx   = (const int*)d_in[1];
    const float* conv_w = (const float*)d_in[2];
    const float* conv_b = (const float*)d_in[3];
    const float* ln_g   = (const float*)d_in[4];
    const float* ln_b   = (const float*)d_in[5];
    const float* head_w = (const float*)d_in[6];
    const float* head_b = (const float*)d_in[7];
    float* out = (float*)d_out;  // [N scores][N*H h]

    const int* src = eidx;
    const int* dst = eidx + N_EDGES;

    // workspace carve-up (4-byte units, 16-elem aligned)
    char* ws = (char*)d_ws;
    size_t o = 0;
    auto alloc = [&](size_t elems) {
        void* p = ws + o * 4;
        o += (elems + 15) & ~(size_t)15;
        return p;
    };
    int*   degcnt  = (int*)alloc(N_NODES);
    float* isd     = (float*)alloc(N_NODES);
    float* ind     = (float*)alloc(N_NODES);
    int*   offs    = (int*)alloc(N_NODES + 1);
    int*   cursor  = (int*)alloc(N_NODES);
    int*   partial = (int*)alloc(N_NODES);
    int*   blocksum= (int*)alloc(256);
    int*   csr_src = (int*)alloc(N_EDGES);
    float* csr_w   = (float*)alloc(N_EDGES);
    float* hw      = (float*)alloc((size_t)N_NODES * HDIM);
    float* hbuf    = (float*)alloc((size_t)N_NODES * HDIM);

    hipMemsetAsync(degcnt, 0, N_NODES * sizeof(int), stream);
    deg_count_kernel<<<(N_EDGES + 255) / 256, 256, 0, stream>>>(dst, degcnt);
    int nblk = (N_NODES + 255) / 256;  // 196
    scan1_kernel<<<nblk, 256, 0, stream>>>(degcnt, partial, blocksum);
    scan2_kernel<<<1, 256, 0, stream>>>(blocksum, nblk);
    scan3_kernel<<<nblk, 256, 0, stream>>>(degcnt, partial, blocksum, offs, cursor, isd, ind);
    fill_kernel<<<(N_EDGES + 255) / 256, 256, 0, stream>>>(src, dst, isd, cursor, csr_src, csr_w);

    const float* hin = x;
    for (int l = 0; l < NLAYERS; ++l) {
        gemm_kernel<<<(N_NODES + BM - 1) / BM, 256, 0, stream>>>(
            hin, conv_w + (size_t)l * HDIM * HDIM, hw);
        float* hout = (l == NLAYERS - 1) ? (out + N_NODES) : hbuf;
        agg_ln_kernel<<<(N_NODES + 3) / 4, 256, 0, stream>>>(
            hw, offs, csr_src, csr_w, ind,
            conv_b + (size_t)l * HDIM, ln_g + (size_t)l * HDIM, ln_b + (size_t)l * HDIM,
            hout, head_w, head_b, out,
            (l < NLAYERS - 1) ? 1 : 0, (l == NLAYERS - 1) ? 1 : 0);
        hin = hout;
    }
}

// Round 2
// 403.616 us; speedup vs baseline: 1.5067x; 1.5067x over previous
//
#include <hip/hip_runtime.h>
#include <math.h>

#define N_NODES 50000
#define N_EDGES 800000
#define HDIM 128
#define NLAYERS 4
#define LN_EPS 1e-5f

typedef __attribute__((ext_vector_type(8))) short short8;
typedef __attribute__((ext_vector_type(4))) float floatx4;

__device__ __forceinline__ ushort f2bf(float x) {
    unsigned b = __float_as_uint(x);
    unsigned r = b + 0x7fffu + ((b >> 16) & 1u);
    return (ushort)(r >> 16);
}
__device__ __forceinline__ float2 bf2f2(unsigned u) {
    return make_float2(__uint_as_float(u << 16), __uint_as_float(u & 0xffff0000u));
}

// ---------------- CSR build ----------------

__global__ void deg_count_kernel(const int* __restrict__ dst, int* __restrict__ degcnt) {
    int e = blockIdx.x * blockDim.x + threadIdx.x;
    if (e < N_EDGES) atomicAdd(&degcnt[dst[e]], 1);
}

__global__ void scan1_kernel(const int* __restrict__ degcnt, int* __restrict__ partial,
                             int* __restrict__ blocksum) {
    __shared__ int buf[256];
    int tid = threadIdx.x;
    int i = blockIdx.x * 256 + tid;
    int v = (i < N_NODES) ? degcnt[i] : 0;
    buf[tid] = v;
    __syncthreads();
    for (int off = 1; off < 256; off <<= 1) {
        int t = (tid >= off) ? buf[tid - off] : 0;
        __syncthreads();
        buf[tid] += t;
        __syncthreads();
    }
    if (i < N_NODES) partial[i] = buf[tid] - v;  // exclusive
    if (tid == 255) blocksum[blockIdx.x] = buf[255];
}

__global__ void scan2_kernel(int* __restrict__ blocksum, int nblk) {
    __shared__ int buf[256];
    int tid = threadIdx.x;
    int v = (tid < nblk) ? blocksum[tid] : 0;
    buf[tid] = v;
    __syncthreads();
    for (int off = 1; off < 256; off <<= 1) {
        int t = (tid >= off) ? buf[tid - off] : 0;
        __syncthreads();
        buf[tid] += t;
        __syncthreads();
    }
    if (tid < nblk) blocksum[tid] = buf[tid] - v;  // exclusive
}

__global__ void scan3_kernel(const int* __restrict__ degcnt, const int* __restrict__ partial,
                             const int* __restrict__ blocksum, int* __restrict__ offs,
                             int* __restrict__ cursor, float* __restrict__ isd,
                             float* __restrict__ ind) {
    int i = blockIdx.x * blockDim.x + threadIdx.x;
    if (i < N_NODES) {
        int o = partial[i] + blocksum[i >> 8];
        offs[i] = o;
        cursor[i] = o;
        float d = (float)degcnt[i] + 1.0f;  // self-loop
        isd[i] = rsqrtf(d);
        ind[i] = 1.0f / d;
        if (i == 0) offs[N_NODES] = N_EDGES;
    }
}

__global__ void fill_kernel(const int* __restrict__ src, const int* __restrict__ dst,
                            const float* __restrict__ isd, int* __restrict__ cursor,
                            int* __restrict__ csr_src, float* __restrict__ csr_w) {
    int e = blockIdx.x * blockDim.x + threadIdx.x;
    if (e < N_EDGES) {
        int s = src[e], d = dst[e];
        int p = atomicAdd(&cursor[d], 1);
        csr_src[p] = s;
        csr_w[p] = isd[s] * isd[d];
    }
}

// ---------------- W -> MFMA B-fragment layout (bf16), once per launch ----------------
// idx = ((l*4 + s)*8 + t)*64 + lane; holds B[k=s*32+(lane>>4)*8+j][n=t*16+(lane&15)], j=0..7
__global__ __launch_bounds__(256) void bprep_kernel(const float* __restrict__ W,
                                                    ushort* __restrict__ bfrag) {
    int idx = blockIdx.x * 256 + threadIdx.x;
    if (idx >= NLAYERS * 4 * 8 * 64) return;
    int lane = idx & 63;
    int t = (idx >> 6) & 7;
    int s = (idx >> 9) & 3;
    int l = idx >> 11;
    int n = t * 16 + (lane & 15);
    int kb = s * 32 + (lane >> 4) * 8;
    const float* Wl = W + (size_t)l * HDIM * HDIM;
    union { uint4 q; ushort u[8]; } o;
#pragma unroll
    for (int j = 0; j < 8; ++j) o.u[j] = f2bf(Wl[(size_t)(kb + j) * HDIM + n]);
    *(uint4*)&bfrag[(size_t)idx * 8] = o.q;
}

// ---------------- GEMM: hw_bf16 = A @ W  via MFMA 16x16x32 bf16 ----------------
// 256 threads = 4 waves; wave computes 16 rows x 128 cols. Block = 64 rows.
template <bool A_FP32>
__global__ __launch_bounds__(256) void gemm_mfma_kernel(const void* __restrict__ Av,
                                                        const ushort* __restrict__ bfrag,
                                                        ushort* __restrict__ out) {
    int wave = threadIdx.x >> 6, lane = threadIdx.x & 63;
    int quad = lane >> 4, mrow = lane & 15;
    int rowBase = blockIdx.x * 64 + wave * 16;
    int arow = rowBase + mrow;
    bool aok = arow < N_NODES;

    floatx4 acc[8];
#pragma unroll
    for (int t = 0; t < 8; ++t) acc[t] = (floatx4)0.f;

#pragma unroll
    for (int s = 0; s < 4; ++s) {
        union { short8 v; ushort u[8]; } af;
        if (A_FP32) {
            const float* A = (const float*)Av;
            if (aok) {
                const float* p = &A[(size_t)arow * HDIM + s * 32 + quad * 8];
#pragma unroll
                for (int j = 0; j < 8; ++j) af.u[j] = f2bf(p[j]);
            } else {
#pragma unroll
                for (int j = 0; j < 8; ++j) af.u[j] = 0;
            }
        } else {
            const ushort* A = (const ushort*)Av;
            if (aok) {
                af.v = *(const short8*)&A[(size_t)arow * HDIM + s * 32 + quad * 8];
            } else {
#pragma unroll
                for (int j = 0; j < 8; ++j) af.u[j] = 0;
            }
        }
#pragma unroll
        for (int t = 0; t < 8; ++t) {
            short8 bf = *(const short8*)&bfrag[(size_t)(((s * 8 + t) * 64) + lane) * 8];
            acc[t] = __builtin_amdgcn_mfma_f32_16x16x32_bf16(af.v, bf, acc[t], 0, 0, 0);
        }
    }
    // C/D layout: col = lane&15 (within 16-col tile t), row = quad*4 + reg
#pragma unroll
    for (int t = 0; t < 8; ++t) {
#pragma unroll
        for (int r = 0; r < 4; ++r) {
            int row = rowBase + quad * 4 + r;
            if (row < N_NODES) out[(size_t)row * HDIM + t * 16 + mrow] = f2bf(acc[t][r]);
        }
    }
}

// ---------------- Fused aggregate + self-loop + bias + LN (+GELU / +head) ----------------
// One wave per node; lane owns 2 columns (one packed bf16 pair = 4 B).
__global__ __launch_bounds__(256) void agg_ln_kernel(
    const unsigned* __restrict__ hwu, const int* __restrict__ offs,
    const int* __restrict__ csr_src, const float* __restrict__ csr_w,
    const float* __restrict__ ind, const float* __restrict__ conv_b,
    const float* __restrict__ ln_g, const float* __restrict__ ln_b,
    unsigned* __restrict__ hout_bf, float* __restrict__ hout_f32,
    const float* __restrict__ head_w, const float* __restrict__ head_b,
    float* __restrict__ scores, int final_layer) {
    int wave = threadIdx.x >> 6;
    int lane = threadIdx.x & 63;
    int n = blockIdx.x * 4 + wave;
    if (n >= N_NODES) return;
    int c = lane * 2;

    float2 hv = bf2f2(hwu[(size_t)n * 64 + lane]);
    float idn = ind[n];
    float2 cb = *(const float2*)&conv_b[c];
    float ax = fmaf(hv.x, idn, cb.x);
    float ay = fmaf(hv.y, idn, cb.y);

    int rs = offs[n], re = offs[n + 1];
    for (int base = rs; base < re; base += 64) {
        int m = re - base;
        if (m > 64) m = 64;
        int sj = 0;
        float wj = 0.f;
        if (lane < m) { sj = csr_src[base + lane]; wj = csr_w[base + lane]; }
        int j = 0;
        for (; j + 4 <= m; j += 4) {
            int s0 = __shfl(sj, j + 0), s1 = __shfl(sj, j + 1);
            int s2 = __shfl(sj, j + 2), s3 = __shfl(sj, j + 3);
            float w0 = __shfl(wj, j + 0), w1 = __shfl(wj, j + 1);
            float w2 = __shfl(wj, j + 2), w3 = __shfl(wj, j + 3);
            unsigned u0 = hwu[(size_t)s0 * 64 + lane];
            unsigned u1 = hwu[(size_t)s1 * 64 + lane];
            unsigned u2 = hwu[(size_t)s2 * 64 + lane];
            unsigned u3 = hwu[(size_t)s3 * 64 + lane];
            float2 v0 = bf2f2(u0), v1 = bf2f2(u1), v2 = bf2f2(u2), v3 = bf2f2(u3);
            ax = fmaf(v0.x, w0, ax); ay = fmaf(v0.y, w0, ay);
            ax = fmaf(v1.x, w1, ax); ay = fmaf(v1.y, w1, ay);
            ax = fmaf(v2.x, w2, ax); ay = fmaf(v2.y, w2, ay);
            ax = fmaf(v3.x, w3, ax); ay = fmaf(v3.y, w3, ay);
        }
        for (; j < m; ++j) {
            int s = __shfl(sj, j);
            float w = __shfl(wj, j);
            float2 v = bf2f2(hwu[(size_t)s * 64 + lane]);
            ax = fmaf(v.x, w, ax);
            ay = fmaf(v.y, w, ay);
        }
    }

    // LayerNorm across 128 columns of the wave (fp32)
    float sum = ax + ay;
#pragma unroll
    for (int o = 32; o; o >>= 1) sum += __shfl_xor(sum, o);
    float mu = sum * (1.0f / HDIM);
    float dx = ax - mu, dy = ay - mu;
    float vs = dx * dx + dy * dy;
#pragma unroll
    for (int o = 32; o; o >>= 1) vs += __shfl_xor(vs, o);
    float rstd = rsqrtf(vs * (1.0f / HDIM) + LN_EPS);
    float2 g = *(const float2*)&ln_g[c];
    float2 b = *(const float2*)&ln_b[c];
    float yx = fmaf(dx * rstd, g.x, b.x);
    float yy = fmaf(dy * rstd, g.y, b.y);

    if (!final_layer) {
        yx = 0.5f * yx * (1.0f + erff(yx * 0.70710678118654752f));
        yy = 0.5f * yy * (1.0f + erff(yy * 0.70710678118654752f));
        hout_bf[(size_t)n * 64 + lane] = (unsigned)f2bf(yx) | ((unsigned)f2bf(yy) << 16);
    } else {
        *(float2*)&hout_f32[(size_t)n * HDIM + c] = make_float2(yx, yy);
        float2 hwv = *(const float2*)&head_w[c];
        float p = yx * hwv.x + yy * hwv.y;
#pragma unroll
        for (int o = 32; o; o >>= 1) p += __shfl_xor(p, o);
        if (lane == 0) scores[n] = p + head_b[0];
    }
}

// ---------------- host ----------------

extern "C" void kernel_launch(void* const* d_in, const int* in_sizes, int n_in,
                              void* d_out, int out_size, void* d_ws, size_t ws_size,
                              hipStream_t stream) {
    const float* x      = (const float*)d_in[0];
    const int*   eidx   = (const int*)d_in[1];
    const float* conv_w = (const float*)d_in[2];
    const float* conv_b = (const float*)d_in[3];
    const float* ln_g   = (const float*)d_in[4];
    const float* ln_b   = (const float*)d_in[5];
    const float* head_w = (const float*)d_in[6];
    const float* head_b = (const float*)d_in[7];
    float* out = (float*)d_out;  // [N scores][N*H h]

    const int* src = eidx;
    const int* dst = eidx + N_EDGES;

    char* ws = (char*)d_ws;
    size_t o = 0;
    auto alloc = [&](size_t elems) {  // elems of 4 bytes
        void* p = ws + o * 4;
        o += (elems + 15) & ~(size_t)15;
        return p;
    };
    int*      degcnt   = (int*)alloc(N_NODES);
    float*    isd      = (float*)alloc(N_NODES);
    float*    ind      = (float*)alloc(N_NODES);
    int*      offs     = (int*)alloc(N_NODES + 1);
    int*      cursor   = (int*)alloc(N_NODES);
    int*      partial  = (int*)alloc(N_NODES);
    int*      blocksum = (int*)alloc(256);
    int*      csr_src  = (int*)alloc(N_EDGES);
    float*    csr_w    = (float*)alloc(N_EDGES);
    ushort*   bfrag    = (ushort*)alloc(NLAYERS * 4 * 8 * 64 * 8 / 2);
    unsigned* hw       = (unsigned*)alloc((size_t)N_NODES * 64);   // bf16 N x 128
    unsigned* hbuf     = (unsigned*)alloc((size_t)N_NODES * 64);   // bf16 N x 128

    hipMemsetAsync(degcnt, 0, N_NODES * sizeof(int), stream);
    deg_count_kernel<<<(N_EDGES + 255) / 256, 256, 0, stream>>>(dst, degcnt);
    int nblk = (N_NODES + 255) / 256;
    scan1_kernel<<<nblk, 256, 0, stream>>>(degcnt, partial, blocksum);
    scan2_kernel<<<1, 256, 0, stream>>>(blocksum, nblk);
    scan3_kernel<<<nblk, 256, 0, stream>>>(degcnt, partial, blocksum, offs, cursor, isd, ind);
    fill_kernel<<<(N_EDGES + 255) / 256, 256, 0, stream>>>(src, dst, isd, cursor, csr_src, csr_w);
    bprep_kernel<<<(NLAYERS * 4 * 8 * 64 + 255) / 256, 256, 0, stream>>>(conv_w, bfrag);

    const void* hin = (const void*)x;
    for (int l = 0; l < NLAYERS; ++l) {
        const ushort* bl = bfrag + (size_t)l * 4 * 8 * 64 * 8;
        if (l == 0)
            gemm_mfma_kernel<true><<<(N_NODES + 63) / 64, 256, 0, stream>>>(hin, bl, (ushort*)hw);
        else
            gemm_mfma_kernel<false><<<(N_NODES + 63) / 64, 256, 0, stream>>>(hin, bl, (ushort*)hw);
        int fin = (l == NLAYERS - 1) ? 1 : 0;
        agg_ln_kernel<<<(N_NODES + 3) / 4, 256, 0, stream>>>(
            hw, offs, csr_src, csr_w, ind,
            conv_b + (size_t)l * HDIM, ln_g + (size_t)l * HDIM, ln_b + (size_t)l * HDIM,
            hbuf, out + N_NODES, head_w, head_b, out, fin);
        hin = (const void*)hbuf;
    }
}

// Round 3
// 370.012 us; speedup vs baseline: 1.6435x; 1.0908x over previous
//
#include <hip/hip_runtime.h>
#include <math.h>

#define N_NODES 50000
#define N_EDGES 800000
#define HDIM 128
#define NLAYERS 4
#define LN_EPS 1e-5f

typedef __attribute__((ext_vector_type(8))) short short8;
typedef __attribute__((ext_vector_type(4))) float floatx4;

__device__ __forceinline__ ushort f2bf(float x) {
    unsigned b = __float_as_uint(x);
    unsigned r = b + 0x7fffu + ((b >> 16) & 1u);
    return (ushort)(r >> 16);
}
__device__ __forceinline__ float2 bf2f2(unsigned u) {
    return make_float2(__uint_as_float(u << 16), __uint_as_float(u & 0xffff0000u));
}

// ---------------- CSR build ----------------

__global__ void deg_count_kernel(const int* __restrict__ dst, int* __restrict__ degcnt) {
    int e = blockIdx.x * blockDim.x + threadIdx.x;
    if (e < N_EDGES) atomicAdd(&degcnt[dst[e]], 1);
}

// Segment allocation: order-free CSR. Per-wave inclusive scan of degrees, one
// global atomicAdd per wave; also computes isd/ind.
__global__ __launch_bounds__(256) void alloc_kernel(
    const int* __restrict__ degcnt, int* __restrict__ counter,
    int* __restrict__ start, int* __restrict__ cursor,
    float* __restrict__ isd, float* __restrict__ ind) {
    int i = blockIdx.x * 256 + threadIdx.x;
    int lane = threadIdx.x & 63;
    int deg = (i < N_NODES) ? degcnt[i] : 0;
    int v = deg;
#pragma unroll
    for (int off = 1; off < 64; off <<= 1) {
        int t = __shfl_up(v, off);
        if (lane >= off) v += t;
    }
    int total = __shfl(v, 63);
    int base = 0;
    if (lane == 63) base = atomicAdd(counter, total);
    base = __shfl(base, 63);
    if (i < N_NODES) {
        int st = base + v - deg;
        start[i] = st;
        cursor[i] = st;
        float d = (float)deg + 1.0f;  // self-loop
        isd[i] = rsqrtf(d);
        ind[i] = 1.0f / d;
    }
}

__global__ void fill_kernel(const int* __restrict__ src, const int* __restrict__ dst,
                            int* __restrict__ cursor, ushort* __restrict__ csr16) {
    int e = blockIdx.x * blockDim.x + threadIdx.x;
    if (e < N_EDGES) {
        int s = src[e], d = dst[e];
        int p = atomicAdd(&cursor[d], 1);
        csr16[p] = (ushort)s;
    }
}

// ---------------- W -> MFMA B-fragment layout (bf16), once per launch ----------------
// idx = ((l*4 + s)*8 + t)*64 + lane; holds B[k=s*32+(lane>>4)*8+j][n=t*16+(lane&15)], j=0..7
__global__ __launch_bounds__(256) void bprep_kernel(const float* __restrict__ W,
                                                    ushort* __restrict__ bfrag) {
    int idx = blockIdx.x * 256 + threadIdx.x;
    if (idx >= NLAYERS * 4 * 8 * 64) return;
    int lane = idx & 63;
    int t = (idx >> 6) & 7;
    int s = (idx >> 9) & 3;
    int l = idx >> 11;
    int n = t * 16 + (lane & 15);
    int kb = s * 32 + (lane >> 4) * 8;
    const float* Wl = W + (size_t)l * HDIM * HDIM;
    union { uint4 q; ushort u[8]; } o;
#pragma unroll
    for (int j = 0; j < 8; ++j) o.u[j] = f2bf(Wl[(size_t)(kb + j) * HDIM + n]);
    *(uint4*)&bfrag[(size_t)idx * 8] = o.q;
}

// ---------------- GEMM: hw_bf16 = A @ W  via MFMA 16x16x32 bf16 ----------------
template <bool A_FP32>
__global__ __launch_bounds__(256) void gemm_mfma_kernel(const void* __restrict__ Av,
                                                        const ushort* __restrict__ bfrag,
                                                        ushort* __restrict__ out) {
    int wave = threadIdx.x >> 6, lane = threadIdx.x & 63;
    int quad = lane >> 4, mrow = lane & 15;
    int rowBase = blockIdx.x * 64 + wave * 16;
    int arow = rowBase + mrow;
    bool aok = arow < N_NODES;

    floatx4 acc[8];
#pragma unroll
    for (int t = 0; t < 8; ++t) acc[t] = (floatx4)0.f;

#pragma unroll
    for (int s = 0; s < 4; ++s) {
        union { short8 v; ushort u[8]; } af;
        if (A_FP32) {
            const float* A = (const float*)Av;
            if (aok) {
                const float* p = &A[(size_t)arow * HDIM + s * 32 + quad * 8];
#pragma unroll
                for (int j = 0; j < 8; ++j) af.u[j] = f2bf(p[j]);
            } else {
#pragma unroll
                for (int j = 0; j < 8; ++j) af.u[j] = 0;
            }
        } else {
            const ushort* A = (const ushort*)Av;
            if (aok) {
                af.v = *(const short8*)&A[(size_t)arow * HDIM + s * 32 + quad * 8];
            } else {
#pragma unroll
                for (int j = 0; j < 8; ++j) af.u[j] = 0;
            }
        }
#pragma unroll
        for (int t = 0; t < 8; ++t) {
            short8 bf = *(const short8*)&bfrag[(size_t)(((s * 8 + t) * 64) + lane) * 8];
            acc[t] = __builtin_amdgcn_mfma_f32_16x16x32_bf16(af.v, bf, acc[t], 0, 0, 0);
        }
    }
    // C/D layout: col = lane&15 (tile t), row = quad*4 + reg
#pragma unroll
    for (int t = 0; t < 8; ++t) {
#pragma unroll
        for (int r = 0; r < 4; ++r) {
            int row = rowBase + quad * 4 + r;
            if (row < N_NODES) out[(size_t)row * HDIM + t * 16 + mrow] = f2bf(acc[t][r]);
        }
    }
}

// ---------------- Fused aggregate + self-loop + bias + LN (+GELU / +head) ----------------
// One wave per node; lane owns 2 columns. Weight factored: isd[n] * sum(isd[s]*hw[s]).
__global__ __launch_bounds__(256) void agg_ln_kernel(
    const unsigned* __restrict__ hwu, const int* __restrict__ start,
    const int* __restrict__ degcnt, const ushort* __restrict__ csr16,
    const float* __restrict__ isd, const float* __restrict__ ind,
    const float* __restrict__ conv_b, const float* __restrict__ ln_g,
    const float* __restrict__ ln_b, unsigned* __restrict__ hout_bf,
    float* __restrict__ hout_f32, const float* __restrict__ head_w,
    const float* __restrict__ head_b, float* __restrict__ scores,
    int final_layer) {
    int wave = threadIdx.x >> 6;
    int lane = threadIdx.x & 63;
    int n = blockIdx.x * 4 + wave;
    if (n >= N_NODES) return;
    int c = lane * 2;

    float2 hv = bf2f2(hwu[(size_t)n * 64 + lane]);
    float isd_n = isd[n];
    float ind_n = ind[n];
    int rs = start[n];
    int deg = degcnt[n];

    float ex = 0.f, ey = 0.f;
    for (int b0 = 0; b0 < deg; b0 += 64) {
        int m = deg - b0;
        if (m > 64) m = 64;
        int sj = 0;
        float wj = 0.f;
        if (lane < m) {
            sj = (int)csr16[rs + b0 + lane];
            wj = isd[sj];
        }
        for (int j = 0; j < m; j += 8) {
            int s0 = __shfl(sj, j + 0), s1 = __shfl(sj, j + 1);
            int s2 = __shfl(sj, j + 2), s3 = __shfl(sj, j + 3);
            int s4 = __shfl(sj, j + 4), s5 = __shfl(sj, j + 5);
            int s6 = __shfl(sj, j + 6), s7 = __shfl(sj, j + 7);
            float w0 = __shfl(wj, j + 0), w1 = __shfl(wj, j + 1);
            float w2 = __shfl(wj, j + 2), w3 = __shfl(wj, j + 3);
            float w4 = __shfl(wj, j + 4), w5 = __shfl(wj, j + 5);
            float w6 = __shfl(wj, j + 6), w7 = __shfl(wj, j + 7);
            unsigned u0 = hwu[(size_t)s0 * 64 + lane];
            unsigned u1 = hwu[(size_t)s1 * 64 + lane];
            unsigned u2 = hwu[(size_t)s2 * 64 + lane];
            unsigned u3 = hwu[(size_t)s3 * 64 + lane];
            unsigned u4 = hwu[(size_t)s4 * 64 + lane];
            unsigned u5 = hwu[(size_t)s5 * 64 + lane];
            unsigned u6 = hwu[(size_t)s6 * 64 + lane];
            unsigned u7 = hwu[(size_t)s7 * 64 + lane];
            float2 v0 = bf2f2(u0), v1 = bf2f2(u1), v2 = bf2f2(u2), v3 = bf2f2(u3);
            float2 v4 = bf2f2(u4), v5 = bf2f2(u5), v6 = bf2f2(u6), v7 = bf2f2(u7);
            ex = fmaf(v0.x, w0, ex); ey = fmaf(v0.y, w0, ey);
            ex = fmaf(v1.x, w1, ex); ey = fmaf(v1.y, w1, ey);
            ex = fmaf(v2.x, w2, ex); ey = fmaf(v2.y, w2, ey);
            ex = fmaf(v3.x, w3, ex); ey = fmaf(v3.y, w3, ey);
            ex = fmaf(v4.x, w4, ex); ey = fmaf(v4.y, w4, ey);
            ex = fmaf(v5.x, w5, ex); ey = fmaf(v5.y, w5, ey);
            ex = fmaf(v6.x, w6, ex); ey = fmaf(v6.y, w6, ey);
            ex = fmaf(v7.x, w7, ex); ey = fmaf(v7.y, w7, ey);
        }
    }
    float2 cb = *(const float2*)&conv_b[c];
    float ax = fmaf(ex, isd_n, fmaf(hv.x, ind_n, cb.x));
    float ay = fmaf(ey, isd_n, fmaf(hv.y, ind_n, cb.y));

    // LayerNorm across 128 columns of the wave (fp32)
    float sum = ax + ay;
#pragma unroll
    for (int o = 32; o; o >>= 1) sum += __shfl_xor(sum, o);
    float mu = sum * (1.0f / HDIM);
    float dx = ax - mu, dy = ay - mu;
    float vs = dx * dx + dy * dy;
#pragma unroll
    for (int o = 32; o; o >>= 1) vs += __shfl_xor(vs, o);
    float rstd = rsqrtf(vs * (1.0f / HDIM) + LN_EPS);
    float2 g = *(const float2*)&ln_g[c];
    float2 b = *(const float2*)&ln_b[c];
    float yx = fmaf(dx * rstd, g.x, b.x);
    float yy = fmaf(dy * rstd, g.y, b.y);

    if (!final_layer) {
        yx = 0.5f * yx * (1.0f + erff(yx * 0.70710678118654752f));
        yy = 0.5f * yy * (1.0f + erff(yy * 0.70710678118654752f));
        hout_bf[(size_t)n * 64 + lane] = (unsigned)f2bf(yx) | ((unsigned)f2bf(yy) << 16);
    } else {
        *(float2*)&hout_f32[(size_t)n * HDIM + c] = make_float2(yx, yy);
        float2 hwv = *(const float2*)&head_w[c];
        float p = yx * hwv.x + yy * hwv.y;
#pragma unroll
        for (int o = 32; o; o >>= 1) p += __shfl_xor(p, o);
        if (lane == 0) scores[n] = p + head_b[0];
    }
}

// ---------------- host ----------------

extern "C" void kernel_launch(void* const* d_in, const int* in_sizes, int n_in,
                              void* d_out, int out_size, void* d_ws, size_t ws_size,
                              hipStream_t stream) {
    const float* x      = (const float*)d_in[0];
    const int*   eidx   = (const int*)d_in[1];
    const float* conv_w = (const float*)d_in[2];
    const float* conv_b = (const float*)d_in[3];
    const float* ln_g   = (const float*)d_in[4];
    const float* ln_b   = (const float*)d_in[5];
    const float* head_w = (const float*)d_in[6];
    const float* head_b = (const float*)d_in[7];
    float* out = (float*)d_out;  // [N scores][N*H h]

    const int* src = eidx;
    const int* dst = eidx + N_EDGES;

    char* ws = (char*)d_ws;
    size_t o = 0;
    auto alloc = [&](size_t elems) {  // elems of 4 bytes
        void* p = ws + o * 4;
        o += (elems + 15) & ~(size_t)15;
        return p;
    };
    int*      degcnt   = (int*)alloc(N_NODES);
    int*      counter  = (int*)alloc(16);
    float*    isd      = (float*)alloc(N_NODES);
    float*    ind      = (float*)alloc(N_NODES);
    int*      start    = (int*)alloc(N_NODES);
    int*      cursor   = (int*)alloc(N_NODES);
    ushort*   csr16    = (ushort*)alloc(N_EDGES / 2);
    ushort*   bfrag    = (ushort*)alloc(NLAYERS * 4 * 8 * 64 * 8 / 2);
    unsigned* hw       = (unsigned*)alloc((size_t)N_NODES * 64);   // bf16 N x 128
    unsigned* hbuf     = (unsigned*)alloc((size_t)N_NODES * 64);   // bf16 N x 128

    // zero degcnt + counter in one memset (contiguous in ws)
    hipMemsetAsync(degcnt, 0, (N_NODES + 16) * sizeof(int), stream);
    deg_count_kernel<<<(N_EDGES + 255) / 256, 256, 0, stream>>>(dst, degcnt);
    int nblk = (N_NODES + 255) / 256;
    alloc_kernel<<<nblk, 256, 0, stream>>>(degcnt, counter, start, cursor, isd, ind);
    fill_kernel<<<(N_EDGES + 255) / 256, 256, 0, stream>>>(src, dst, cursor, csr16);
    bprep_kernel<<<(NLAYERS * 4 * 8 * 64 + 255) / 256, 256, 0, stream>>>(conv_w, bfrag);

    const void* hin = (const void*)x;
    for (int l = 0; l < NLAYERS; ++l) {
        const ushort* bl = bfrag + (size_t)l * 4 * 8 * 64 * 8;
        if (l == 0)
            gemm_mfma_kernel<true><<<(N_NODES + 63) / 64, 256, 0, stream>>>(hin, bl, (ushort*)hw);
        else
            gemm_mfma_kernel<false><<<(N_NODES + 63) / 64, 256, 0, stream>>>(hin, bl, (ushort*)hw);
        int fin = (l == NLAYERS - 1) ? 1 : 0;
        agg_ln_kernel<<<(N_NODES + 3) / 4, 256, 0, stream>>>(
            hw, start, degcnt, csr16, isd, ind,
            conv_b + (size_t)l * HDIM, ln_g + (size_t)l * HDIM, ln_b + (size_t)l * HDIM,
            hbuf, out + N_NODES, head_w, head_b, out, fin);
        hin = (const void*)hbuf;
    }
}